// Round 3
// baseline (826.182 us; speedup 1.0000x reference)
//
#include <hip/hip_runtime.h>
#include <hip/hip_bf16.h>

typedef __bf16 bf16;
typedef __attribute__((ext_vector_type(8))) __bf16 bf16x8;
typedef __attribute__((ext_vector_type(4))) __bf16 bf16x4;
typedef __attribute__((ext_vector_type(4))) float f32x4;

#define MFMA_16x16x32(a, b, c) __builtin_amdgcn_mfma_f32_16x16x32_bf16(a, b, c, 0, 0, 0)

// Problem dims (fixed by the reference)
#define BATCH 4
#define SEQ   4096
#define HID   256
#define FFD   1024
#define MTOT  (BATCH * SEQ)   // 16384

// ---------------- prep kernels ----------------
__global__ void cast_x_kernel(const float* __restrict__ src, bf16* __restrict__ dst, int n4) {
    int i = blockIdx.x * blockDim.x + threadIdx.x;
    if (i < n4) {
        float4 v = ((const float4*)src)[i];
        bf16x4 o;
        o[0] = (bf16)v.x; o[1] = (bf16)v.y; o[2] = (bf16)v.z; o[3] = (bf16)v.w;
        ((bf16x4*)dst)[i] = o;
    }
}

// src: fp32 [R][C]  ->  dst: bf16 [C][R]   (dst[c][r] = src[r][c])
__global__ void transpose_cast_kernel(const float* __restrict__ src, bf16* __restrict__ dst,
                                      int R, int C) {
    int idx = blockIdx.x * blockDim.x + threadIdx.x;
    if (idx < R * C) {
        int r = idx / C, c = idx % C;
        dst[c * R + r] = (bf16)src[idx];
    }
}

// ---------------- QKV projection ----------------
// grid (MTOT/64, 12); blockIdx.y: 0-3 -> q cols, 4-7 -> k cols, 8-11 -> v cols
__global__ __launch_bounds__(256) void qkv_kernel(
    const bf16* __restrict__ xb,                       // [MTOT][256]
    const bf16* __restrict__ wqT, const bf16* __restrict__ wkT, const bf16* __restrict__ wvT,
    const float* __restrict__ bq, const float* __restrict__ bk, const float* __restrict__ bv,
    bf16* __restrict__ q, bf16* __restrict__ k, bf16* __restrict__ vT) // q,k: [MTOT][256]; vT: [B][256][SEQ]
{
    __shared__ bf16 vt[64][72];
    const int lane = threadIdx.x & 63, wave = threadIdx.x >> 6;
    const int g = lane >> 4, c = lane & 15;
    const int mat = blockIdx.y >> 2;
    const int n0 = (blockIdx.y & 3) * 64;
    const int mblk = blockIdx.x * 64;
    const int m0 = mblk + wave * 16;
    const bf16* wT = (mat == 0) ? wqT : (mat == 1) ? wkT : wvT;
    const float* bias = (mat == 0) ? bq : (mat == 1) ? bk : bv;

    f32x4 acc[4] = {};
    #pragma unroll
    for (int ks = 0; ks < 8; ++ks) {
        bf16x8 a = *(const bf16x8*)(xb + (size_t)(m0 + c) * 256 + ks * 32 + 8 * g);
        #pragma unroll
        for (int nf = 0; nf < 4; ++nf) {
            bf16x8 b = *(const bf16x8*)(wT + (size_t)(n0 + nf * 16 + c) * 256 + ks * 32 + 8 * g);
            acc[nf] = MFMA_16x16x32(a, b, acc[nf]);
        }
    }
    if (mat < 2) {
        bf16* out = (mat == 0) ? q : k;
        #pragma unroll
        for (int nf = 0; nf < 4; ++nf) {
            int n = n0 + nf * 16 + c;
            float bs = bias[n];
            #pragma unroll
            for (int r = 0; r < 4; ++r)
                out[(size_t)(m0 + 4 * g + r) * 256 + n] = (bf16)(acc[nf][r] + bs);
        }
    } else {
        #pragma unroll
        for (int nf = 0; nf < 4; ++nf) {
            int n = n0 + nf * 16 + c;
            float bs = bias[n];
            #pragma unroll
            for (int r = 0; r < 4; ++r)
                vt[nf * 16 + c][wave * 16 + 4 * g + r] = (bf16)(acc[nf][r] + bs);
        }
        __syncthreads();
        int bt = mblk >> 12;        // /SEQ
        int s0 = mblk & (SEQ - 1);
        int nl = threadIdx.x >> 2;  // 0..63 -> col (n offset)
        int sc = (threadIdx.x & 3) * 16;  // row (s offset) chunk
        bf16* dst = vT + ((size_t)bt * 256 + n0 + nl) * SEQ + s0 + sc;
        const bf16x8* sp = (const bf16x8*)&vt[nl][sc];
        ((bf16x8*)dst)[0] = sp[0];
        ((bf16x8*)dst)[1] = sp[1];
    }
}

// ---------------- fused attention (flash-style) ----------------
// grid: BATCH * SEQ/64 blocks; each wave owns 16 q rows.
__global__ __launch_bounds__(256) void attn_kernel(
    const bf16* __restrict__ qb, const bf16* __restrict__ kb, const bf16* __restrict__ vT,
    bf16* __restrict__ attn_bf)
{
    __shared__ bf16 p_lds[4][16][40];
    const int lane = threadIdx.x & 63, wave = threadIdx.x >> 6;
    const int g = lane >> 4, c = lane & 15;
    const int bt = blockIdx.x >> 6;
    const int q0 = (blockIdx.x & 63) * 64 + wave * 16;
    const int mrow = bt * SEQ + q0;

    bf16x8 qf[8];
    #pragma unroll
    for (int ks = 0; ks < 8; ++ks)
        qf[ks] = *(const bf16x8*)(qb + (size_t)(mrow + c) * 256 + ks * 32 + 8 * g);

    f32x4 o[16] = {};
    float m_run[4], l_run[4];
    #pragma unroll
    for (int r = 0; r < 4; ++r) { m_run[r] = -1e30f; l_run[r] = 0.f; }

    const bf16* kbase = kb + (size_t)bt * SEQ * 256;
    const bf16* vbase = vT + (size_t)bt * 256 * SEQ;

    for (int kv0 = 0; kv0 < SEQ; kv0 += 32) {
        f32x4 s[2] = {};
        #pragma unroll
        for (int ks = 0; ks < 8; ++ks) {
            #pragma unroll
            for (int nf = 0; nf < 2; ++nf) {
                bf16x8 b = *(const bf16x8*)(kbase + (size_t)(kv0 + nf * 16 + c) * 256 + ks * 32 + 8 * g);
                s[nf] = MFMA_16x16x32(qf[ks], b, s[nf]);
            }
        }
        // online softmax per row (row = 4g+r); kv values spread over 16 lanes (c) x 2 frags
        float al[4];
        #pragma unroll
        for (int r = 0; r < 4; ++r) {
            float v0 = s[0][r] * 0.0625f, v1 = s[1][r] * 0.0625f;
            float mx = fmaxf(v0, v1);
            mx = fmaxf(mx, __shfl_xor(mx, 1));
            mx = fmaxf(mx, __shfl_xor(mx, 2));
            mx = fmaxf(mx, __shfl_xor(mx, 4));
            mx = fmaxf(mx, __shfl_xor(mx, 8));
            float mn = fmaxf(m_run[r], mx);
            float a_ = __expf(m_run[r] - mn);
            float p0 = __expf(v0 - mn), p1 = __expf(v1 - mn);
            s[0][r] = p0; s[1][r] = p1;
            float ls = p0 + p1;
            ls += __shfl_xor(ls, 1); ls += __shfl_xor(ls, 2);
            ls += __shfl_xor(ls, 4); ls += __shfl_xor(ls, 8);
            m_run[r] = mn; l_run[r] = l_run[r] * a_ + ls; al[r] = a_;
        }
        #pragma unroll
        for (int nf = 0; nf < 16; ++nf)
            #pragma unroll
            for (int r = 0; r < 4; ++r)
                o[nf][r] *= al[r];
        // P: regs (q=4g+r, kv=nf*16+c) -> LDS -> A-frag (q=c, kv=8g+j)
        #pragma unroll
        for (int nf = 0; nf < 2; ++nf)
            #pragma unroll
            for (int r = 0; r < 4; ++r)
                p_lds[wave][4 * g + r][nf * 16 + c] = (bf16)s[nf][r];
        __syncthreads();   // hard compiler+HW ordering (uniform trip count; wave-private data)
        bf16x8 pa = *(const bf16x8*)&p_lds[wave][c][8 * g];
        #pragma unroll
        for (int nf = 0; nf < 16; ++nf) {
            bf16x8 b = *(const bf16x8*)(vbase + (size_t)(nf * 16 + c) * SEQ + kv0 + 8 * g);
            o[nf] = MFMA_16x16x32(pa, b, o[nf]);
        }
        __syncthreads();   // keep iterations cleanly separated
    }
    #pragma unroll
    for (int r = 0; r < 4; ++r) l_run[r] = 1.f / l_run[r];
    #pragma unroll
    for (int nf = 0; nf < 16; ++nf) {
        #pragma unroll
        for (int r = 0; r < 4; ++r) {
            float v = o[nf][r] * l_run[r];
            attn_bf[(size_t)(mrow + 4 * g + r) * 256 + nf * 16 + c] = (bf16)v;
        }
    }
}

// ---------------- FFN1: h = relu(attn @ w1 + b1)  (M-half pass) ----------------
__global__ __launch_bounds__(256) void ffn1_kernel(
    const bf16* __restrict__ attn, const bf16* __restrict__ w1T, const float* __restrict__ b1,
    bf16* __restrict__ h, int m_base)
{
    const int lane = threadIdx.x & 63, wave = threadIdx.x >> 6;
    const int g = lane >> 4, c = lane & 15;
    const int m0 = m_base + blockIdx.x * 64 + wave * 16;
    const int n0 = blockIdx.y * 64;

    f32x4 acc[4] = {};
    #pragma unroll
    for (int ks = 0; ks < 8; ++ks) {
        bf16x8 a = *(const bf16x8*)(attn + (size_t)(m0 + c) * 256 + ks * 32 + 8 * g);
        #pragma unroll
        for (int nf = 0; nf < 4; ++nf) {
            bf16x8 b = *(const bf16x8*)(w1T + (size_t)(n0 + nf * 16 + c) * 256 + ks * 32 + 8 * g);
            acc[nf] = MFMA_16x16x32(a, b, acc[nf]);
        }
    }
    #pragma unroll
    for (int nf = 0; nf < 4; ++nf) {
        int n = n0 + nf * 16 + c;
        float bs = b1[n];
        #pragma unroll
        for (int r = 0; r < 4; ++r) {
            float v = fmaxf(acc[nf][r] + bs, 0.f);
            h[(size_t)(m0 - m_base + 4 * g + r) * FFD + n] = (bf16)v;
        }
    }
}

// ---------------- FFN2 + residual + LayerNorm  (M-half pass) ----------------
// NOTE: d_out is FP32 (reference output dtype is float32) — this was the
// round-1/2 failure: writing bf16 into a float* buffer.
__global__ __launch_bounds__(256) void ffn2_ln_kernel(
    const bf16* __restrict__ h, const bf16* __restrict__ w2T, const float* __restrict__ b2,
    const bf16* __restrict__ attn_bf, const float* __restrict__ ln_g, const float* __restrict__ ln_b,
    float* __restrict__ out, int m_base)
{
    const int lane = threadIdx.x & 63, wave = threadIdx.x >> 6;
    const int g = lane >> 4, c = lane & 15;
    const int m0 = m_base + blockIdx.x * 64 + wave * 16;
    const int mloc = m0 - m_base;

    f32x4 acc[16] = {};
    for (int ks = 0; ks < 32; ++ks) {
        bf16x8 a = *(const bf16x8*)(h + (size_t)(mloc + c) * FFD + ks * 32 + 8 * g);
        #pragma unroll
        for (int nf = 0; nf < 16; ++nf) {
            bf16x8 b = *(const bf16x8*)(w2T + (size_t)(nf * 16 + c) * FFD + ks * 32 + 8 * g);
            acc[nf] = MFMA_16x16x32(a, b, acc[nf]);
        }
    }
    // residual + bias
    #pragma unroll
    for (int nf = 0; nf < 16; ++nf) {
        int col = nf * 16 + c;
        float bs = b2[col];
        #pragma unroll
        for (int r = 0; r < 4; ++r)
            acc[nf][r] += bs + (float)attn_bf[(size_t)(m0 + 4 * g + r) * 256 + col];
    }
    // LayerNorm stats per row (row = m0 + 4g + r; elements over 16 lanes x 16 frags)
    float sum[4] = {}, sq[4] = {};
    #pragma unroll
    for (int nf = 0; nf < 16; ++nf)
        #pragma unroll
        for (int r = 0; r < 4; ++r) { sum[r] += acc[nf][r]; sq[r] += acc[nf][r] * acc[nf][r]; }
    float mean[4], rstd[4];
    #pragma unroll
    for (int r = 0; r < 4; ++r) {
        float s_ = sum[r], q_ = sq[r];
        s_ += __shfl_xor(s_, 1); s_ += __shfl_xor(s_, 2); s_ += __shfl_xor(s_, 4); s_ += __shfl_xor(s_, 8);
        q_ += __shfl_xor(q_, 1); q_ += __shfl_xor(q_, 2); q_ += __shfl_xor(q_, 4); q_ += __shfl_xor(q_, 8);
        mean[r] = s_ * (1.f / 256.f);
        float var = q_ * (1.f / 256.f) - mean[r] * mean[r];
        rstd[r] = rsqrtf(var + 1e-5f);
    }
    #pragma unroll
    for (int nf = 0; nf < 16; ++nf) {
        int col = nf * 16 + c;
        float gg = ln_g[col], bb = ln_b[col];
        #pragma unroll
        for (int r = 0; r < 4; ++r)
            out[(size_t)(m0 + 4 * g + r) * 256 + col] = (acc[nf][r] - mean[r]) * rstd[r] * gg + bb;
    }
}

// ---------------- launch ----------------
// ws layout (bytes), total ~34 MB:
//   0        wqT (128K)   131072 wkT   262144 wvT
//   393216   w1T (512K)   917504 w2T (512K)      [end 1441792]
//   2097152  xb  (8M)  -> reused as attn_bf after qkv
//   10485760 qb  (8M) \
//   18874368 kb  (8M) /  -> reused as h (16M, half-M at a time) after attn
//   27262976 vT  (8M)    [end 35651584]
extern "C" void kernel_launch(void* const* d_in, const int* in_sizes, int n_in,
                              void* d_out, int out_size, void* d_ws, size_t ws_size,
                              hipStream_t stream) {
    const float* x    = (const float*)d_in[0];
    const float* wq   = (const float*)d_in[1];
    const float* bq   = (const float*)d_in[2];
    const float* wk   = (const float*)d_in[3];
    const float* bk   = (const float*)d_in[4];
    const float* wv   = (const float*)d_in[5];
    const float* bv   = (const float*)d_in[6];
    const float* w1   = (const float*)d_in[7];
    const float* b1   = (const float*)d_in[8];
    const float* w2   = (const float*)d_in[9];
    const float* b2   = (const float*)d_in[10];
    const float* ln_g = (const float*)d_in[11];
    const float* ln_b = (const float*)d_in[12];
    float* out = (float*)d_out;   // fp32 output

    char* ws = (char*)d_ws;
    bf16* wqT = (bf16*)(ws + 0);
    bf16* wkT = (bf16*)(ws + 131072);
    bf16* wvT = (bf16*)(ws + 262144);
    bf16* w1T = (bf16*)(ws + 393216);
    bf16* w2T = (bf16*)(ws + 917504);
    bf16* xb  = (bf16*)(ws + 2097152);
    bf16* qb  = (bf16*)(ws + 10485760);
    bf16* kb  = (bf16*)(ws + 18874368);
    bf16* vT  = (bf16*)(ws + 27262976);
    bf16* attn_bf = xb;   // xb dead after qkv
    bf16* hbuf    = qb;   // qb+kb dead after attn; 16 MB = half-M of h

    cast_x_kernel<<<(MTOT * HID / 4 + 255) / 256, 256, 0, stream>>>(x, xb, MTOT * HID / 4);
    transpose_cast_kernel<<<(HID * HID + 255) / 256, 256, 0, stream>>>(wq, wqT, HID, HID);
    transpose_cast_kernel<<<(HID * HID + 255) / 256, 256, 0, stream>>>(wk, wkT, HID, HID);
    transpose_cast_kernel<<<(HID * HID + 255) / 256, 256, 0, stream>>>(wv, wvT, HID, HID);
    transpose_cast_kernel<<<(HID * FFD + 255) / 256, 256, 0, stream>>>(w1, w1T, HID, FFD);
    transpose_cast_kernel<<<(FFD * HID + 255) / 256, 256, 0, stream>>>(w2, w2T, FFD, HID);

    qkv_kernel<<<dim3(MTOT / 64, 12), 256, 0, stream>>>(xb, wqT, wkT, wvT, bq, bk, bv, qb, kb, vT);
    attn_kernel<<<BATCH * SEQ / 64, 256, 0, stream>>>(qb, kb, vT, attn_bf);

    const int HALF = MTOT / 2;
    for (int p = 0; p < 2; ++p) {
        ffn1_kernel<<<dim3(HALF / 64, FFD / 64), 256, 0, stream>>>(attn_bf, w1T, b1, hbuf, p * HALF);
        ffn2_ln_kernel<<<HALF / 64, 256, 0, stream>>>(hbuf, w2T, b2, attn_bf, ln_g, ln_b, out, p * HALF);
    }
}

// Round 6
// 741.143 us; speedup vs baseline: 1.1147x; 1.1147x over previous
//
#include <hip/hip_runtime.h>
#include <hip/hip_bf16.h>

typedef __bf16 bf16;
typedef __attribute__((ext_vector_type(8))) __bf16 bf16x8;
typedef __attribute__((ext_vector_type(4))) __bf16 bf16x4;
typedef __attribute__((ext_vector_type(4))) float f32x4;

#define MFMA_16x16x32(a, b, c) __builtin_amdgcn_mfma_f32_16x16x32_bf16(a, b, c, 0, 0, 0)

// Problem dims (fixed by the reference)
#define BATCH 4
#define SEQ   4096
#define HID   256
#define FFD   1024
#define MTOT  (BATCH * SEQ)   // 16384

// ---------------- prep kernels ----------------
__global__ void cast_x_kernel(const float* __restrict__ src, bf16* __restrict__ dst, int n4) {
    int i = blockIdx.x * blockDim.x + threadIdx.x;
    if (i < n4) {
        float4 v = ((const float4*)src)[i];
        bf16x4 o;
        o[0] = (bf16)v.x; o[1] = (bf16)v.y; o[2] = (bf16)v.z; o[3] = (bf16)v.w;
        ((bf16x4*)dst)[i] = o;
    }
}

// src: fp32 [R][C]  ->  dst: bf16 [C][R]   (dst[c][r] = src[r][c])
__global__ void transpose_cast_kernel(const float* __restrict__ src, bf16* __restrict__ dst,
                                      int R, int C) {
    int idx = blockIdx.x * blockDim.x + threadIdx.x;
    if (idx < R * C) {
        int r = idx / C, c = idx % C;
        dst[c * R + r] = (bf16)src[idx];
    }
}

// ---------------- QKV projection ----------------
// grid (MTOT/64, 12); blockIdx.y: 0-3 -> q cols, 4-7 -> k cols, 8-11 -> v cols
__global__ __launch_bounds__(256) void qkv_kernel(
    const bf16* __restrict__ xb,                       // [MTOT][256]
    const bf16* __restrict__ wqT, const bf16* __restrict__ wkT, const bf16* __restrict__ wvT,
    const float* __restrict__ bq, const float* __restrict__ bk, const float* __restrict__ bv,
    bf16* __restrict__ q, bf16* __restrict__ k, bf16* __restrict__ vT) // q,k: [MTOT][256]; vT: [B][256][SEQ]
{
    __shared__ bf16 vt[64][72];
    const int lane = threadIdx.x & 63, wave = threadIdx.x >> 6;
    const int g = lane >> 4, c = lane & 15;
    const int mat = blockIdx.y >> 2;
    const int n0 = (blockIdx.y & 3) * 64;
    const int mblk = blockIdx.x * 64;
    const int m0 = mblk + wave * 16;
    const bf16* wT = (mat == 0) ? wqT : (mat == 1) ? wkT : wvT;
    const float* bias = (mat == 0) ? bq : (mat == 1) ? bk : bv;

    f32x4 acc[4] = {};
    #pragma unroll
    for (int ks = 0; ks < 8; ++ks) {
        bf16x8 a = *(const bf16x8*)(xb + (size_t)(m0 + c) * 256 + ks * 32 + 8 * g);
        #pragma unroll
        for (int nf = 0; nf < 4; ++nf) {
            bf16x8 b = *(const bf16x8*)(wT + (size_t)(n0 + nf * 16 + c) * 256 + ks * 32 + 8 * g);
            acc[nf] = MFMA_16x16x32(a, b, acc[nf]);
        }
    }
    if (mat < 2) {
        bf16* out = (mat == 0) ? q : k;
        #pragma unroll
        for (int nf = 0; nf < 4; ++nf) {
            int n = n0 + nf * 16 + c;
            float bs = bias[n];
            #pragma unroll
            for (int r = 0; r < 4; ++r)
                out[(size_t)(m0 + 4 * g + r) * 256 + n] = (bf16)(acc[nf][r] + bs);
        }
    } else {
        #pragma unroll
        for (int nf = 0; nf < 4; ++nf) {
            int n = n0 + nf * 16 + c;
            float bs = bias[n];
            #pragma unroll
            for (int r = 0; r < 4; ++r)
                vt[nf * 16 + c][wave * 16 + 4 * g + r] = (bf16)(acc[nf][r] + bs);
        }
        __syncthreads();
        int bt = mblk >> 12;        // /SEQ
        int s0 = mblk & (SEQ - 1);
        int nl = threadIdx.x >> 2;  // 0..63 -> col (n offset)
        int sc = (threadIdx.x & 3) * 16;  // row (s offset) chunk
        bf16* dst = vT + ((size_t)bt * 256 + n0 + nl) * SEQ + s0 + sc;
        const bf16x8* sp = (const bf16x8*)&vt[nl][sc];
        ((bf16x8*)dst)[0] = sp[0];
        ((bf16x8*)dst)[1] = sp[1];
    }
}

// ---------------- fused attention (flash-style, 1 wave/block, reg-pipelined) ----------------
// grid: 1024 blocks x 64 threads; each wave owns 16 q rows, full KV sweep.
// K/V tiles live in registers, double-buffered K (2-deep pipeline via compiler vmcnt).

#define LOAD_K(KF, KV)  do {                                                              \
    _Pragma("unroll")                                                                     \
    for (int ks_ = 0; ks_ < 8; ++ks_) {                                                   \
        _Pragma("unroll")                                                                 \
        for (int nf_ = 0; nf_ < 2; ++nf_)                                                 \
            KF[ks_ * 2 + nf_] = *(const bf16x8*)(kbase + (size_t)((KV) + nf_ * 16 + c) * 256 + ks_ * 32 + 8 * g); \
    } } while (0)

#define LOAD_V(KV)  do {                                                                  \
    _Pragma("unroll")                                                                     \
    for (int nf_ = 0; nf_ < 16; ++nf_)                                                    \
        vf[nf_] = *(const bf16x8*)(vbase + (size_t)(nf_ * 16 + c) * SEQ + (KV) + 8 * g);  \
    } while (0)

#define ATTN_BODY(KF)  do {                                                               \
    f32x4 s0 = {}, s1 = {};                                                               \
    __builtin_amdgcn_s_setprio(1);                                                        \
    _Pragma("unroll")                                                                     \
    for (int ks_ = 0; ks_ < 8; ++ks_) {                                                   \
        s0 = MFMA_16x16x32(qf[ks_], KF[ks_ * 2 + 0], s0);                                 \
        s1 = MFMA_16x16x32(qf[ks_], KF[ks_ * 2 + 1], s1);                                 \
    }                                                                                     \
    __builtin_amdgcn_s_setprio(0);                                                        \
    float al[4];                                                                          \
    _Pragma("unroll")                                                                     \
    for (int r_ = 0; r_ < 4; ++r_) {                                                      \
        float v0 = s0[r_] * 0.0625f, v1 = s1[r_] * 0.0625f;                               \
        float mx = fmaxf(v0, v1);                                                         \
        mx = fmaxf(mx, __shfl_xor(mx, 1));                                                \
        mx = fmaxf(mx, __shfl_xor(mx, 2));                                                \
        mx = fmaxf(mx, __shfl_xor(mx, 4));                                                \
        mx = fmaxf(mx, __shfl_xor(mx, 8));                                                \
        float mn = fmaxf(m_run[r_], mx);                                                  \
        float a_ = __expf(m_run[r_] - mn);                                                \
        float p0 = __expf(v0 - mn), p1 = __expf(v1 - mn);                                 \
        p_lds[4 * g + r_][c]      = (bf16)p0;                                             \
        p_lds[4 * g + r_][16 + c] = (bf16)p1;                                             \
        float ls = p0 + p1;                                                               \
        ls += __shfl_xor(ls, 1); ls += __shfl_xor(ls, 2);                                 \
        ls += __shfl_xor(ls, 4); ls += __shfl_xor(ls, 8);                                 \
        m_run[r_] = mn; l_run[r_] = l_run[r_] * a_ + ls; al[r_] = a_;                     \
    }                                                                                     \
    _Pragma("unroll")                                                                     \
    for (int nf_ = 0; nf_ < 16; ++nf_)                                                    \
        { _Pragma("unroll") for (int r_ = 0; r_ < 4; ++r_) o[nf_][r_] *= al[r_]; }        \
    __syncthreads();  /* order P ds_writes before pa ds_read */                           \
    bf16x8 pa = *(const bf16x8*)&p_lds[c][8 * g];                                         \
    __builtin_amdgcn_s_setprio(1);                                                        \
    _Pragma("unroll")                                                                     \
    for (int nf_ = 0; nf_ < 16; ++nf_)                                                    \
        o[nf_] = MFMA_16x16x32(pa, vf[nf_], o[nf_]);                                      \
    __builtin_amdgcn_s_setprio(0);                                                        \
    __syncthreads();  /* order pa ds_read before next tile's P ds_writes */               \
} while (0)

__global__ __launch_bounds__(64, 1) void attn_kernel(
    const bf16* __restrict__ qb, const bf16* __restrict__ kb, const bf16* __restrict__ vT,
    bf16* __restrict__ attn_bf)
{
    __shared__ bf16 p_lds[16][40];
    const int lane = threadIdx.x;
    const int g = lane >> 4, c = lane & 15;
    // bijective XCD swizzle (1024 % 8 == 0): XCD x gets contiguous range -> one batch's K/V (4MB) per L2
    const int swz = (blockIdx.x & 7) * 128 + (blockIdx.x >> 3);
    const int bt = swz >> 8;
    const int q0 = (swz & 255) * 16;
    const int mrow = bt * SEQ + q0;

    bf16x8 qf[8];
    #pragma unroll
    for (int ks = 0; ks < 8; ++ks)
        qf[ks] = *(const bf16x8*)(qb + (size_t)(mrow + c) * 256 + ks * 32 + 8 * g);

    f32x4 o[16] = {};
    float m_run[4], l_run[4];
    #pragma unroll
    for (int r = 0; r < 4; ++r) { m_run[r] = -1e30f; l_run[r] = 0.f; }

    const bf16* kbase = kb + (size_t)bt * SEQ * 256;
    const bf16* vbase = vT + (size_t)bt * 256 * SEQ;

    bf16x8 kfA[16], kfB[16], vf[16];
    LOAD_K(kfA, 0);
    #pragma unroll 1
    for (int kv0 = 0; kv0 < SEQ; kv0 += 64) {
        LOAD_V(kv0);
        LOAD_K(kfB, kv0 + 32);
        ATTN_BODY(kfA);
        LOAD_V(kv0 + 32);
        if (kv0 + 64 < SEQ) LOAD_K(kfA, kv0 + 64);
        ATTN_BODY(kfB);
    }

    #pragma unroll
    for (int r = 0; r < 4; ++r) l_run[r] = 1.f / l_run[r];
    #pragma unroll
    for (int nf = 0; nf < 16; ++nf) {
        #pragma unroll
        for (int r = 0; r < 4; ++r) {
            float v = o[nf][r] * l_run[r];
            attn_bf[(size_t)(mrow + 4 * g + r) * 256 + nf * 16 + c] = (bf16)v;
        }
    }
}

// ---------------- FFN1: h = relu(attn @ w1 + b1)  (M-half pass) ----------------
__global__ __launch_bounds__(256) void ffn1_kernel(
    const bf16* __restrict__ attn, const bf16* __restrict__ w1T, const float* __restrict__ b1,
    bf16* __restrict__ h, int m_base)
{
    const int lane = threadIdx.x & 63, wave = threadIdx.x >> 6;
    const int g = lane >> 4, c = lane & 15;
    const int m0 = m_base + blockIdx.x * 64 + wave * 16;
    const int n0 = blockIdx.y * 64;

    f32x4 acc[4] = {};
    #pragma unroll
    for (int ks = 0; ks < 8; ++ks) {
        bf16x8 a = *(const bf16x8*)(attn + (size_t)(m0 + c) * 256 + ks * 32 + 8 * g);
        #pragma unroll
        for (int nf = 0; nf < 4; ++nf) {
            bf16x8 b = *(const bf16x8*)(w1T + (size_t)(n0 + nf * 16 + c) * 256 + ks * 32 + 8 * g);
            acc[nf] = MFMA_16x16x32(a, b, acc[nf]);
        }
    }
    #pragma unroll
    for (int nf = 0; nf < 4; ++nf) {
        int n = n0 + nf * 16 + c;
        float bs = b1[n];
        #pragma unroll
        for (int r = 0; r < 4; ++r) {
            float v = fmaxf(acc[nf][r] + bs, 0.f);
            h[(size_t)(m0 - m_base + 4 * g + r) * FFD + n] = (bf16)v;
        }
    }
}

// ---------------- FFN2 + residual + LayerNorm  (EXACT round-3 version, proven PASS) ----------------
// d_out is FP32 (reference output dtype is float32).
__global__ __launch_bounds__(256) void ffn2_ln_kernel(
    const bf16* __restrict__ h, const bf16* __restrict__ w2T, const float* __restrict__ b2,
    const bf16* __restrict__ attn_bf, const float* __restrict__ ln_g, const float* __restrict__ ln_b,
    float* __restrict__ out, int m_base)
{
    const int lane = threadIdx.x & 63, wave = threadIdx.x >> 6;
    const int g = lane >> 4, c = lane & 15;
    const int m0 = m_base + blockIdx.x * 64 + wave * 16;
    const int mloc = m0 - m_base;

    f32x4 acc[16] = {};
    for (int ks = 0; ks < 32; ++ks) {
        bf16x8 a = *(const bf16x8*)(h + (size_t)(mloc + c) * FFD + ks * 32 + 8 * g);
        #pragma unroll
        for (int nf = 0; nf < 16; ++nf) {
            bf16x8 b = *(const bf16x8*)(w2T + (size_t)(nf * 16 + c) * FFD + ks * 32 + 8 * g);
            acc[nf] = MFMA_16x16x32(a, b, acc[nf]);
        }
    }
    // residual + bias
    #pragma unroll
    for (int nf = 0; nf < 16; ++nf) {
        int col = nf * 16 + c;
        float bs = b2[col];
        #pragma unroll
        for (int r = 0; r < 4; ++r)
            acc[nf][r] += bs + (float)attn_bf[(size_t)(m0 + 4 * g + r) * 256 + col];
    }
    // LayerNorm stats per row (row = m0 + 4g + r; elements over 16 lanes x 16 frags)
    float sum[4] = {}, sq[4] = {};
    #pragma unroll
    for (int nf = 0; nf < 16; ++nf)
        #pragma unroll
        for (int r = 0; r < 4; ++r) { sum[r] += acc[nf][r]; sq[r] += acc[nf][r] * acc[nf][r]; }
    float mean[4], rstd[4];
    #pragma unroll
    for (int r = 0; r < 4; ++r) {
        float s_ = sum[r], q_ = sq[r];
        s_ += __shfl_xor(s_, 1); s_ += __shfl_xor(s_, 2); s_ += __shfl_xor(s_, 4); s_ += __shfl_xor(s_, 8);
        q_ += __shfl_xor(q_, 1); q_ += __shfl_xor(q_, 2); q_ += __shfl_xor(q_, 4); q_ += __shfl_xor(q_, 8);
        mean[r] = s_ * (1.f / 256.f);
        float var = q_ * (1.f / 256.f) - mean[r] * mean[r];
        rstd[r] = rsqrtf(var + 1e-5f);
    }
    #pragma unroll
    for (int nf = 0; nf < 16; ++nf) {
        int col = nf * 16 + c;
        float gg = ln_g[col], bb = ln_b[col];
        #pragma unroll
        for (int r = 0; r < 4; ++r)
            out[(size_t)(m0 + 4 * g + r) * 256 + col] = (acc[nf][r] - mean[r]) * rstd[r] * gg + bb;
    }
}

// ---------------- launch ----------------
// ws layout (bytes), total ~34 MB (proven to fit: round-3 PASS used end=35651584):
//   0        wqT (128K)   131072 wkT   262144 wvT
//   393216   w1T (512K)   917504 w2T (512K)      [end 1441792]
//   2097152  xb  (8M)  -> reused as attn_bf after qkv
//   10485760 qb  (8M) \
//   18874368 kb  (8M) /  -> reused as h (16M, half-M at a time) after attn
//   27262976 vT  (8M)    [end 35651584]
extern "C" void kernel_launch(void* const* d_in, const int* in_sizes, int n_in,
                              void* d_out, int out_size, void* d_ws, size_t ws_size,
                              hipStream_t stream) {
    const float* x    = (const float*)d_in[0];
    const float* wq   = (const float*)d_in[1];
    const float* bq   = (const float*)d_in[2];
    const float* wk   = (const float*)d_in[3];
    const float* bk   = (const float*)d_in[4];
    const float* wv   = (const float*)d_in[5];
    const float* bv   = (const float*)d_in[6];
    const float* w1   = (const float*)d_in[7];
    const float* b1   = (const float*)d_in[8];
    const float* w2   = (const float*)d_in[9];
    const float* b2   = (const float*)d_in[10];
    const float* ln_g = (const float*)d_in[11];
    const float* ln_b = (const float*)d_in[12];
    float* out = (float*)d_out;   // fp32 output

    char* ws = (char*)d_ws;
    bf16* wqT = (bf16*)(ws + 0);
    bf16* wkT = (bf16*)(ws + 131072);
    bf16* wvT = (bf16*)(ws + 262144);
    bf16* w1T = (bf16*)(ws + 393216);
    bf16* w2T = (bf16*)(ws + 917504);
    bf16* xb  = (bf16*)(ws + 2097152);
    bf16* qb  = (bf16*)(ws + 10485760);
    bf16* kb  = (bf16*)(ws + 18874368);
    bf16* vT  = (bf16*)(ws + 27262976);
    bf16* attn_bf = xb;   // xb dead after qkv
    bf16* hbuf    = qb;   // qb+kb dead after attn; 16 MB = half-M of h

    cast_x_kernel<<<(MTOT * HID / 4 + 255) / 256, 256, 0, stream>>>(x, xb, MTOT * HID / 4);
    transpose_cast_kernel<<<(HID * HID + 255) / 256, 256, 0, stream>>>(wq, wqT, HID, HID);
    transpose_cast_kernel<<<(HID * HID + 255) / 256, 256, 0, stream>>>(wk, wkT, HID, HID);
    transpose_cast_kernel<<<(HID * HID + 255) / 256, 256, 0, stream>>>(wv, wvT, HID, HID);
    transpose_cast_kernel<<<(HID * FFD + 255) / 256, 256, 0, stream>>>(w1, w1T, HID, FFD);
    transpose_cast_kernel<<<(FFD * HID + 255) / 256, 256, 0, stream>>>(w2, w2T, FFD, HID);

    qkv_kernel<<<dim3(MTOT / 64, 12), 256, 0, stream>>>(xb, wqT, wkT, wvT, bq, bk, bv, qb, kb, vT);
    attn_kernel<<<MTOT / 16, 64, 0, stream>>>(qb, kb, vT, attn_bf);

    const int HALF = MTOT / 2;
    for (int p = 0; p < 2; ++p) {
        ffn1_kernel<<<dim3(HALF / 64, FFD / 64), 256, 0, stream>>>(attn_bf, w1T, b1, hbuf, p * HALF);
        ffn2_ln_kernel<<<HALF / 64, 256, 0, stream>>>(hbuf, w2T, b2, attn_bf, ln_g, ln_b, out, p * HALF);
    }
}